// Round 15
// baseline (122.335 us; speedup 1.0000x reference)
//
#include <hip/hip_runtime.h>
#include <math.h>
#include <stdint.h>

#define D    128
#define CCLS 64
#define CH   16     // column chunks; grid = (M/128) x CH
#define HB   8      // histogram partial blocks

typedef _Float16 f16x8 __attribute__((ext_vector_type(8)));
typedef float    f32x4 __attribute__((ext_vector_type(4)));

__device__ __forceinline__ float wave_reduce_sum(float v) {
    #pragma unroll
    for (int off = 32; off > 0; off >>= 1) v += __shfl_xor(v, off, 64);
    return v;
}

__device__ __forceinline__ void gload_lds16(const void* g, void* l) {
    __builtin_amdgcn_global_load_lds(
        (const __attribute__((address_space(1))) uint32_t*)g,
        (__attribute__((address_space(3))) uint32_t*)l, 16, 0, 0);
}
__device__ __forceinline__ void gload_lds4(const void* g, void* l) {
    __builtin_amdgcn_global_load_lds(
        (const __attribute__((address_space(1))) uint32_t*)g,
        (__attribute__((address_space(3))) uint32_t*)l, 4, 0, 0);
}

// --- normalize rows; histogram partials; labs. (identical to R14) ----------
__global__ void norm_kernel(const float* __restrict__ protos,
                            const float* __restrict__ proj2,
                            const float* __restrict__ proj3,
                            const int* __restrict__ t2, const int* __restrict__ t3,
                            _Float16* __restrict__ ftile, int* __restrict__ labs,
                            float* __restrict__ hpart, float* __restrict__ loss_sum,
                            int* __restrict__ ticket, int N, int M) {
    const float SCL = 3.8017368953f;  // sqrt(10 * log2(e))
    int w = threadIdx.x >> 6;
    int lane = threadIdx.x & 63;
    int row = blockIdx.x * (blockDim.x >> 6) + w;
    const int MT = M + 128;

    if (blockIdx.x < HB) {             // partial class histogram
        __shared__ int h[CCLS];
        int t = threadIdx.x;
        if (t < CCLS) h[t] = 0;
        __syncthreads();
        int base = blockIdx.x * (M / HB);
        for (int i = t; i < M / HB; i += (int)blockDim.x) {
            int gi = base + i;
            int lab = (gi < N) ? t2[gi] : t3[gi - N];
            atomicAdd(&h[lab], 1);
        }
        __syncthreads();
        if (t < CCLS) hpart[blockIdx.x * CCLS + t] = (float)h[t];
    }
    if (blockIdx.x == HB && threadIdx.x == 0) { loss_sum[0] = 0.f; ticket[0] = 0; }

    if (row < MT) {
        const float* src = nullptr;
        if (row < M)             src = (row < N) ? proj2 + (size_t)row * D
                                                 : proj3 + (size_t)(row - N) * D;
        else if (row < M + CCLS) src = protos + (size_t)(row - M) * D;
        float2 v = {0.f, 0.f};
        if (src) v = ((const float2*)src)[lane];
        float ss = wave_reduce_sum(v.x * v.x + v.y * v.y);
        float scale = src ? SCL / fmaxf(sqrtf(ss), 1e-12f) : 0.f;
        _Float16 h0 = (_Float16)(v.x * scale), h1 = (_Float16)(v.y * scale);
        int k0 = 2 * lane;
        size_t off = ((size_t)(row >> 4) * 16 + (k0 >> 3)) * 128 + (row & 15) * 8 + (k0 & 7);
        ftile[off] = h0; ftile[off + 1] = h1;
        if (row < M && lane == 0)
            labs[row] = (row < N) ? t2[row] : t3[row - N];
    }
}

#define SIM_BODY(REPS, NPART, DPART, RPBUF)                                        \
    __shared__ _Float16 bbuf[3][4096];                                             \
    __shared__ int labL[512];                                                      \
    const int panel = blockIdx.x;                                                  \
    const int chunk = blockIdx.y;                                                  \
    const int t = threadIdx.x;                                                     \
    const int w = t >> 6, lane = t & 63;                                           \
    const int g = lane >> 4, li = lane & 15;                                       \
    const int lo = g * 128 + li * 8;                                               \
    const int rtA = panel * 8 + w * 2;                                             \
    const int nH = 16;                                                             \
    const int sBase = chunk * 8;                                                   \
    const int row0 = panel * 128 + 32 * w + li;                                    \
    const int rl0 = labs[row0];                                                    \
    const int rl1 = labs[row0 + 16];                                               \
    f16x8 a[2][4];                                                                 \
    _Pragma("unroll")                                                              \
    for (int m = 0; m < 2; ++m)                                                    \
        _Pragma("unroll")                                                          \
        for (int kt = 0; kt < 4; ++kt)                                             \
            a[m][kt] = *(const f16x8*)(ftile + (size_t)(rtA + m) * 2048 + kt * 512 + lo); \
    float rn[2] = {0.f, 0.f}, rd[2] = {0.f, 0.f};                                  \
    {                                                                              \
        const char* lsrc = (const char*)labs + (size_t)sBase * 256;                \
        _Pragma("unroll")                                                          \
        for (int c = 0; c < 2; ++c) {                                              \
            int cc = w * 2 + c;                                                    \
            gload_lds4(lsrc + cc * 256 + lane * 4, (char*)labL + cc * 256);        \
        }                                                                          \
    }                                                                              \
    const int diagS = 2 * panel + (w >> 1);                                        \
    const int nD0 = 2 * (w & 1);                                                   \
    for (int rep = 0; rep < (REPS); ++rep) {                                       \
        __syncthreads();                                                           \
        STAGE_H(0, 0);                                                             \
        STAGE_H(1, 1);                                                             \
        for (int h = 0; h < nH; ++h) {                                             \
            if (h < nH - 1) { asm volatile("s_waitcnt vmcnt(2)" ::: "memory"); }   \
            else            { asm volatile("s_waitcnt vmcnt(0)" ::: "memory"); }   \
            __builtin_amdgcn_s_barrier();                                          \
            const _Float16* Bl = &bbuf[h % 3][0];                                  \
            const int s = sBase + (h >> 1);                                        \
            const bool isDiag = (s == diagS);                                      \
            const int nBase = (h & 1) * 2;                                         \
            _Pragma("unroll")                                                      \
            for (int nl = 0; nl < 2; ++nl) {                                       \
                f16x8 bn[4];                                                       \
                _Pragma("unroll")                                                  \
                for (int kt = 0; kt < 4; ++kt)                                     \
                    bn[kt] = *(const f16x8*)(Bl + nl * 2048 + kt * 512 + lo);      \
                f32x4 acc[2];                                                      \
                _Pragma("unroll")                                                  \
                for (int m = 0; m < 2; ++m)                                        \
                    _Pragma("unroll")                                              \
                    for (int r = 0; r < 4; ++r) acc[m][r] = 0.f;                   \
                _Pragma("unroll")                                                  \
                for (int kt = 0; kt < 4; ++kt)                                     \
                    _Pragma("unroll")                                              \
                    for (int m = 0; m < 2; ++m)                                    \
                        acc[m] = __builtin_amdgcn_mfma_f32_16x16x32_f16(bn[kt], a[m][kt], acc[m], 0, 0, 0); \
                if (isDiag) {                                                      \
                    _Pragma("unroll")                                              \
                    for (int m = 0; m < 2; ++m)                                    \
                        _Pragma("unroll")                                          \
                        for (int r = 0; r < 4; ++r)                                \
                            acc[m][r] = (nBase + nl == nD0 + m && 4 * g + r == li) \
                                        ? -1e5f : acc[m][r];                       \
                }                                                                  \
                int4 c4 = *(const int4*)(labL + h * 32 + nl * 16 + 4 * g);         \
                _Pragma("unroll")                                                  \
                for (int m = 0; m < 2; ++m) {                                      \
                    float e0 = __builtin_amdgcn_exp2f(acc[m][0]);                  \
                    float e1 = __builtin_amdgcn_exp2f(acc[m][1]);                  \
                    float e2 = __builtin_amdgcn_exp2f(acc[m][2]);                  \
                    float e3 = __builtin_amdgcn_exp2f(acc[m][3]);                  \
                    const int rl = m ? rl1 : rl0;                                  \
                    rd[m] += e0 + e1 + e2 + e3;                                    \
                    rn[m] += (c4.x == rl) ? e0 : 0.f;                              \
                    rn[m] += (c4.y == rl) ? e1 : 0.f;                              \
                    rn[m] += (c4.z == rl) ? e2 : 0.f;                              \
                    rn[m] += (c4.w == rl) ? e3 : 0.f;                              \
                }                                                                  \
            }                                                                      \
            if (h + 2 < nH) STAGE_H((h + 2) % 3, h + 2);                           \
        }                                                                          \
    }                                                                              \
    float rpacc[2] = {0.f, 0.f};                                                   \
    if (chunk == 0) {                                                              \
        const int rbp = M >> 4;                                                    \
        _Pragma("unroll")                                                          \
        for (int n = 0; n < 4; ++n) {                                              \
            f16x8 bn[4];                                                           \
            _Pragma("unroll")                                                      \
            for (int kt = 0; kt < 4; ++kt)                                         \
                bn[kt] = *(const f16x8*)(ftile + (size_t)(rbp + n) * 2048 + kt * 512 + lo); \
            f32x4 acc[2];                                                          \
            _Pragma("unroll")                                                      \
            for (int m = 0; m < 2; ++m)                                            \
                _Pragma("unroll")                                                  \
                for (int r = 0; r < 4; ++r) acc[m][r] = 0.f;                       \
            _Pragma("unroll")                                                      \
            for (int kt = 0; kt < 4; ++kt)                                         \
                _Pragma("unroll")                                                  \
                for (int m = 0; m < 2; ++m)                                        \
                    acc[m] = __builtin_amdgcn_mfma_f32_16x16x32_f16(bn[kt], a[m][kt], acc[m], 0, 0, 0); \
            f32x4 fr = {1.0f + 1e-6f, 1.0f + 1e-6f, 1.0f + 1e-6f, 1.0f + 1e-6f};   \
            _Pragma("unroll")                                                      \
            for (int b = 0; b < HB; ++b)                                           \
                fr += *(const f32x4*)(hpart + b * CCLS + 16 * n + 4 * g);          \
            const int c0 = 16 * n + 4 * g;                                         \
            _Pragma("unroll")                                                      \
            for (int m = 0; m < 2; ++m) {                                          \
                float e0 = __builtin_amdgcn_exp2f(acc[m][0]);                      \
                float e1 = __builtin_amdgcn_exp2f(acc[m][1]);                      \
                float e2 = __builtin_amdgcn_exp2f(acc[m][2]);                      \
                float e3 = __builtin_amdgcn_exp2f(acc[m][3]);                      \
                const int rl = m ? rl1 : rl0;                                      \
                rpacc[m] += e0 / fr[0] + e1 / fr[1] + e2 / fr[2] + e3 / fr[3];     \
                rn[m] += (c0 + 0 == rl) ? e0 : 0.f;                                \
                rn[m] += (c0 + 1 == rl) ? e1 : 0.f;                                \
                rn[m] += (c0 + 2 == rl) ? e2 : 0.f;                                \
                rn[m] += (c0 + 3 == rl) ? e3 : 0.f;                                \
            }                                                                      \
        }                                                                          \
    }                                                                              \
    _Pragma("unroll")                                                              \
    for (int m = 0; m < 2; ++m) {                                                  \
        rn[m] += __shfl_xor(rn[m], 16, 64); rn[m] += __shfl_xor(rn[m], 32, 64);    \
        rd[m] += __shfl_xor(rd[m], 16, 64); rd[m] += __shfl_xor(rd[m], 32, 64);    \
        if (chunk == 0) {                                                          \
            rpacc[m] += __shfl_xor(rpacc[m], 16, 64);                              \
            rpacc[m] += __shfl_xor(rpacc[m], 32, 64);                              \
        }                                                                          \
    }                                                                              \
    if (lane < 16) {                                                               \
        _Pragma("unroll")                                                          \
        for (int m = 0; m < 2; ++m) {                                              \
            const int rowm = row0 + 16 * m;                                        \
            NPART[(size_t)chunk * M + rowm] = rn[m];                               \
            DPART[(size_t)chunk * M + rowm] = rd[m];                               \
            if (chunk == 0) RPBUF[rowm] = rpacc[m];                                \
        }                                                                          \
    }

#define STAGE_H(buf, h)                                                       \
    {                                                                         \
        const char* src_ = (const char*)ftile + (size_t)sBase * 16384         \
                           + (size_t)(h) * 8192;                              \
        char* dst_ = (char*)&bbuf[(buf)][0];                                  \
        _Pragma("unroll")                                                     \
        for (int c = 0; c < 2; ++c) {                                         \
            int j_ = w * 2 + c;                                               \
            gload_lds16(src_ + (size_t)j_ * 1024 + lane * 16,                 \
                        dst_ + (size_t)j_ * 1024);                            \
        }                                                                     \
    }

// --- real sim: identical schedule to R14 (REPS=1) ---------------------------
__global__ __launch_bounds__(256, 4)
void sim_kernel(const _Float16* __restrict__ ftile,
                const int* __restrict__ labs,
                const float* __restrict__ hpart,
                float* __restrict__ nPart, float* __restrict__ dPart,
                float* __restrict__ rp, int M) {
    SIM_BODY(1, nPart, dPart, rp)
}

// --- MEASUREMENT PROBE: exact same body run 4x, writing to scrap buffers.
//     new_total - 37.5us = 4 x cost(sim); probe surfaces in rocprof top-5
//     with full counters (MfmaUtil/VALUBusy/VGPR/conflicts) for diagnosis.
__global__ __launch_bounds__(256, 4)
void sim_probe4x_kernel(const _Float16* __restrict__ ftile,
                        const int* __restrict__ labs,
                        const float* __restrict__ hpart,
                        float* __restrict__ nPart, float* __restrict__ dPart,
                        float* __restrict__ rp, int M) {
    SIM_BODY(4, nPart, dPart, rp)
}

// --- per-row loss + mean accumulate; last block writes output ----------------
__global__ void fin_kernel(const int* __restrict__ labs,
                           const float* __restrict__ hpart,
                           const float* __restrict__ nPart,
                           const float* __restrict__ dPart,
                           const float* __restrict__ rp,
                           float* __restrict__ loss_sum, int* __restrict__ ticket,
                           float* __restrict__ out, int M) {
    int i = blockIdx.x * blockDim.x + threadIdx.x;
    float l = 0.f;
    if (i < M) {
        float rnT = 0.f, rdT = 0.f;
        #pragma unroll
        for (int ch = 0; ch < CH; ++ch) {
            rnT += nPart[(size_t)ch * M + i];
            rdT += dPart[(size_t)ch * M + i];
        }
        int lab = labs[i];
        float fsum = 1.0f + 1e-6f;
        #pragma unroll
        for (int b = 0; b < HB; ++b) fsum += hpart[b * CCLS + lab];
        float denom = rdT / fsum + rp[i];
        l = logf(denom + 1e-12f) - logf(rnT);
    }
    l = wave_reduce_sum(l);
    __shared__ float ws_[4];
    if ((threadIdx.x & 63) == 0) ws_[threadIdx.x >> 6] = l;
    __syncthreads();
    if (threadIdx.x == 0) {
        atomicAdd(loss_sum, ws_[0] + ws_[1] + ws_[2] + ws_[3]);
        __threadfence();
        int old = atomicAdd(ticket, 1);
        if (old == (int)gridDim.x - 1) {
            __threadfence();
            out[0] = *(volatile float*)loss_sum / (float)M;
        }
    }
}

extern "C" void kernel_launch(void* const* d_in, const int* in_sizes, int n_in,
                              void* d_out, int out_size, void* d_ws, size_t ws_size,
                              hipStream_t stream) {
    const float* protos = (const float*)d_in[0];
    const float* proj2  = (const float*)d_in[1];
    const int*   t2     = (const int*)d_in[2];
    const float* proj3  = (const float*)d_in[3];
    const int*   t3     = (const int*)d_in[4];
    float* out = (float*)d_out;

    const int N = in_sizes[1] / D;   // 4096
    const int M = 2 * N;             // 8192
    const int MT = M + 128;

    _Float16* ftile = (_Float16*)d_ws;                 // MT*D halfs (1KB-tiled)
    int*   labs     = (int*)(ftile + (size_t)MT * D);  // M ints
    float* hpart    = (float*)(labs + M);              // HB*CCLS
    float* nPart    = hpart + HB * CCLS;               // CH*M
    float* dPart    = nPart + (size_t)CH * M;          // CH*M
    float* rp       = dPart + (size_t)CH * M;          // M
    float* loss_sum = rp + M;                          // 1
    int*   ticket   = (int*)(loss_sum + 1);            // 1
    float* nProbe   = (float*)(ticket + 1);            // CH*M
    float* dProbe   = nProbe + (size_t)CH * M;         // CH*M
    float* rpProbe  = dProbe + (size_t)CH * M;         // M

    norm_kernel<<<(MT + 3) / 4, 256, 0, stream>>>(protos, proj2, proj3, t2, t3,
                                                  ftile, labs, hpart, loss_sum,
                                                  ticket, N, M);
    dim3 grid(M / 128, CH);
    sim_kernel<<<grid, 256, 0, stream>>>(ftile, labs, hpart, nPart, dPart, rp, M);
    fin_kernel<<<(M + 255) / 256, 256, 0, stream>>>(labs, hpart, nPart, dPart, rp,
                                                    loss_sum, ticket, out, M);
    sim_probe4x_kernel<<<grid, 256, 0, stream>>>(ftile, labs, hpart,
                                                 nProbe, dProbe, rpProbe, M);
}

// Round 16
// 88.431 us; speedup vs baseline: 1.3834x; 1.3834x over previous
//
#include <hip/hip_runtime.h>
#include <math.h>
#include <stdint.h>

#define D    128
#define CCLS 64
#define HB   8      // histogram partial blocks

typedef _Float16 f16x8 __attribute__((ext_vector_type(8)));
typedef float    f32x4 __attribute__((ext_vector_type(4)));

__device__ __forceinline__ float wave_reduce_sum(float v) {
    #pragma unroll
    for (int off = 32; off > 0; off >>= 1) v += __shfl_xor(v, off, 64);
    return v;
}

__device__ __forceinline__ void gload_lds16(const void* g, void* l) {
    __builtin_amdgcn_global_load_lds(
        (const __attribute__((address_space(1))) uint32_t*)g,
        (__attribute__((address_space(3))) uint32_t*)l, 16, 0, 0);
}

// --- normalize rows; histogram partials; labs. (same as R14) ----------------
__global__ void norm_kernel(const float* __restrict__ protos,
                            const float* __restrict__ proj2,
                            const float* __restrict__ proj3,
                            const int* __restrict__ t2, const int* __restrict__ t3,
                            _Float16* __restrict__ ftile, int* __restrict__ labs,
                            float* __restrict__ hpart, float* __restrict__ loss_sum,
                            int* __restrict__ ticket, int N, int M) {
    const float SCL = 3.8017368953f;  // sqrt(10 * log2(e))
    int w = threadIdx.x >> 6;
    int lane = threadIdx.x & 63;
    int row = blockIdx.x * (blockDim.x >> 6) + w;
    const int MT = M + 128;

    if (blockIdx.x < HB) {             // partial class histogram
        __shared__ int h[CCLS];
        int t = threadIdx.x;
        if (t < CCLS) h[t] = 0;
        __syncthreads();
        int base = blockIdx.x * (M / HB);
        for (int i = t; i < M / HB; i += (int)blockDim.x) {
            int gi = base + i;
            int lab = (gi < N) ? t2[gi] : t3[gi - N];
            atomicAdd(&h[lab], 1);
        }
        __syncthreads();
        if (t < CCLS) hpart[blockIdx.x * CCLS + t] = (float)h[t];
    }
    if (blockIdx.x == HB && threadIdx.x == 0) { loss_sum[0] = 0.f; ticket[0] = 0; }

    if (row < MT) {
        const float* src = nullptr;
        if (row < M)             src = (row < N) ? proj2 + (size_t)row * D
                                                 : proj3 + (size_t)(row - N) * D;
        else if (row < M + CCLS) src = protos + (size_t)(row - M) * D;
        float2 v = {0.f, 0.f};
        if (src) v = ((const float2*)src)[lane];
        float ss = wave_reduce_sum(v.x * v.x + v.y * v.y);
        float scale = src ? SCL / fmaxf(sqrtf(ss), 1e-12f) : 0.f;
        _Float16 h0 = (_Float16)(v.x * scale), h1 = (_Float16)(v.y * scale);
        int k0 = 2 * lane;
        size_t off = ((size_t)(row >> 4) * 16 + (k0 >> 3)) * 128 + (row & 15) * 8 + (k0 & 7);
        ftile[off] = h0; ftile[off + 1] = h1;
        if (row < M && lane == 0)
            labs[row] = (row < N) ? t2[row] : t3[row - N];
    }
}

// --- main: SYMMETRIC pair blocks. Block = unordered panel pair (pi <= pj),
//     computes the 128x128 exp-tile ONCE (halves total elements: exp2, MFMA,
//     LDS, row-sum VALU all halved -- R15 probe showed VALUBusy 54% was the
//     binder). Row sums (panel pi) lane-local as before -> slot pj.
//     Column sums (panel pj) via per-lane rcd/rcn[4] (static idx), li-group
//     shfl fold per n-slice, LDS colp, 128-thread final fold -> slot pi.
//     Diagonal blocks mask i==j and fuse the proto slice. No in-loop
//     barriers: whole 32KB B-panel staged once via global_load_lds.
__global__ __launch_bounds__(256, 4)
void sim_kernel(const _Float16* __restrict__ ftile,
                const int* __restrict__ labs,
                const float* __restrict__ hpart,
                float* __restrict__ nPart, float* __restrict__ dPart,
                float* __restrict__ rp, int M) {
    __shared__ __align__(16) _Float16 Bl[16384];   // 32KB: pj panel fragments
    __shared__ int labL[128];
    __shared__ float colp[4][2][4][32];            // [wave][d/n][r][n*4+g]

    const int P = M / 128;                          // 64 panels
    int b = blockIdx.x, pi = 0, rem = P;
    while (b >= rem) { b -= rem; --rem; ++pi; }
    const int pj = pi + b;
    const bool diagB = (pi == pj);

    const int t = threadIdx.x;
    const int w = t >> 6, lane = t & 63;
    const int g = lane >> 4, li = lane & 15;
    const int lo = g * 128 + li * 8;

    // stage B-panel (32KB contiguous in tiled layout) + pj labels
    {
        const char* src = (const char*)(ftile + (size_t)pj * 16384);
        char* dst = (char*)Bl;
        #pragma unroll
        for (int q = 0; q < 8; ++q)
            gload_lds16(src + (size_t)(w * 8 + q) * 1024 + lane * 16,
                        dst + (size_t)(w * 8 + q) * 1024);
    }
    if (t >= 128) labL[t - 128] = labs[pj * 128 + (t - 128)];

    // A fragments: this wave's 32 rows x 128 k (direct from L2)
    const int rtA = pi * 8 + w * 2;
    f16x8 a[2][4];
    #pragma unroll
    for (int m = 0; m < 2; ++m)
        #pragma unroll
        for (int kt = 0; kt < 4; ++kt)
            a[m][kt] = *(const f16x8*)(ftile + (size_t)(rtA + m) * 2048 + kt * 512 + lo);

    const int row0 = pi * 128 + 32 * w + li;
    const int rl0 = labs[row0];
    const int rl1 = labs[row0 + 16];
    float rn[2] = {0.f, 0.f}, rd[2] = {0.f, 0.f};

    __syncthreads();   // drains global_load_lds (vmcnt) + labL writes

    #pragma unroll
    for (int n = 0; n < 8; ++n) {
        f16x8 bn[4];
        #pragma unroll
        for (int kt = 0; kt < 4; ++kt)
            bn[kt] = *(const f16x8*)(Bl + n * 2048 + kt * 512 + lo);

        f32x4 acc[2];
        #pragma unroll
        for (int m = 0; m < 2; ++m)
            #pragma unroll
            for (int r = 0; r < 4; ++r) acc[m][r] = 0.f;

        #pragma unroll
        for (int kt = 0; kt < 4; ++kt)
            #pragma unroll
            for (int m = 0; m < 2; ++m)
                acc[m] = __builtin_amdgcn_mfma_f32_16x16x32_f16(bn[kt], a[m][kt], acc[m], 0, 0, 0);

        if (diagB) {   // i==j mask: row's 16-block is 2w+m; col block is n
            #pragma unroll
            for (int m = 0; m < 2; ++m)
                #pragma unroll
                for (int r = 0; r < 4; ++r)
                    acc[m][r] = (n == 2 * w + m && 4 * g + r == li) ? -1e5f : acc[m][r];
        }

        int4 c4 = *(const int4*)(labL + n * 16 + 4 * g);
        float rcd[4] = {0.f, 0.f, 0.f, 0.f};
        float rcn[4] = {0.f, 0.f, 0.f, 0.f};
        #pragma unroll
        for (int m = 0; m < 2; ++m) {
            float e0 = __builtin_amdgcn_exp2f(acc[m][0]);
            float e1 = __builtin_amdgcn_exp2f(acc[m][1]);
            float e2 = __builtin_amdgcn_exp2f(acc[m][2]);
            float e3 = __builtin_amdgcn_exp2f(acc[m][3]);
            const int rl = m ? rl1 : rl0;
            float s0 = (c4.x == rl) ? e0 : 0.f;
            float s1 = (c4.y == rl) ? e1 : 0.f;
            float s2 = (c4.z == rl) ? e2 : 0.f;
            float s3 = (c4.w == rl) ? e3 : 0.f;
            rd[m] += (e0 + e1) + (e2 + e3);
            rn[m] += (s0 + s1) + (s2 + s3);
            rcd[0] += e0; rcd[1] += e1; rcd[2] += e2; rcd[3] += e3;
            rcn[0] += s0; rcn[1] += s1; rcn[2] += s2; rcn[3] += s3;
        }

        if (!diagB) {
            #pragma unroll
            for (int r = 0; r < 4; ++r) {
                #pragma unroll
                for (int off = 1; off < 16; off <<= 1) {
                    rcd[r] += __shfl_xor(rcd[r], off, 64);
                    rcn[r] += __shfl_xor(rcn[r], off, 64);
                }
            }
            if (li == 0) {
                #pragma unroll
                for (int r = 0; r < 4; ++r) {
                    colp[w][0][r][n * 4 + g] = rcd[r];
                    colp[w][1][r][n * 4 + g] = rcn[r];
                }
            }
        }
    }

    // proto slice (diag blocks only): rp = sum_c e/freq_c; numer += e[lab]
    float rpacc[2] = {0.f, 0.f};
    if (diagB) {
        const int rbp = M >> 4;
        #pragma unroll
        for (int n = 0; n < 4; ++n) {
            f16x8 bn[4];
            #pragma unroll
            for (int kt = 0; kt < 4; ++kt)
                bn[kt] = *(const f16x8*)(ftile + (size_t)(rbp + n) * 2048 + kt * 512 + lo);
            f32x4 acc[2];
            #pragma unroll
            for (int m = 0; m < 2; ++m)
                #pragma unroll
                for (int r = 0; r < 4; ++r) acc[m][r] = 0.f;
            #pragma unroll
            for (int kt = 0; kt < 4; ++kt)
                #pragma unroll
                for (int m = 0; m < 2; ++m)
                    acc[m] = __builtin_amdgcn_mfma_f32_16x16x32_f16(bn[kt], a[m][kt], acc[m], 0, 0, 0);

            f32x4 fr = {1.0f + 1e-6f, 1.0f + 1e-6f, 1.0f + 1e-6f, 1.0f + 1e-6f};
            #pragma unroll
            for (int hb = 0; hb < HB; ++hb)
                fr += *(const f32x4*)(hpart + hb * CCLS + 16 * n + 4 * g);
            const int c0 = 16 * n + 4 * g;
            #pragma unroll
            for (int m = 0; m < 2; ++m) {
                float e0 = __builtin_amdgcn_exp2f(acc[m][0]);
                float e1 = __builtin_amdgcn_exp2f(acc[m][1]);
                float e2 = __builtin_amdgcn_exp2f(acc[m][2]);
                float e3 = __builtin_amdgcn_exp2f(acc[m][3]);
                const int rl = m ? rl1 : rl0;
                rpacc[m] += e0 / fr[0] + e1 / fr[1] + e2 / fr[2] + e3 / fr[3];
                rn[m] += (c0 + 0 == rl) ? e0 : 0.f;
                rn[m] += (c0 + 1 == rl) ? e1 : 0.f;
                rn[m] += (c0 + 2 == rl) ? e2 : 0.f;
                rn[m] += (c0 + 3 == rl) ? e3 : 0.f;
            }
        }
    }

    // row side: reduce over g, store slot pj
    #pragma unroll
    for (int m = 0; m < 2; ++m) {
        rn[m] += __shfl_xor(rn[m], 16, 64); rn[m] += __shfl_xor(rn[m], 32, 64);
        rd[m] += __shfl_xor(rd[m], 16, 64); rd[m] += __shfl_xor(rd[m], 32, 64);
        if (diagB) {
            rpacc[m] += __shfl_xor(rpacc[m], 16, 64);
            rpacc[m] += __shfl_xor(rpacc[m], 32, 64);
        }
    }
    if (lane < 16) {
        #pragma unroll
        for (int m = 0; m < 2; ++m) {
            const int rowm = row0 + 16 * m;
            nPart[(size_t)pj * M + rowm] = rn[m];
            dPart[(size_t)pj * M + rowm] = rd[m];
            if (diagB) rp[rowm] = rpacc[m];
        }
    }

    // col side: cross-wave fold, store slot pi (rows of panel pj)
    __syncthreads();
    if (!diagB && t < 128) {
        const int j = t, nn = j >> 4, gg = (j >> 2) & 3, rr = j & 3;
        float sd = colp[0][0][rr][nn * 4 + gg] + colp[1][0][rr][nn * 4 + gg]
                 + colp[2][0][rr][nn * 4 + gg] + colp[3][0][rr][nn * 4 + gg];
        float sn = colp[0][1][rr][nn * 4 + gg] + colp[1][1][rr][nn * 4 + gg]
                 + colp[2][1][rr][nn * 4 + gg] + colp[3][1][rr][nn * 4 + gg];
        dPart[(size_t)pi * M + pj * 128 + j] = sd;
        nPart[(size_t)pi * M + pj * 128 + j] = sn;
    }
}

// --- per-row loss + mean accumulate; last block writes output ----------------
__global__ void fin_kernel(const int* __restrict__ labs,
                           const float* __restrict__ hpart,
                           const float* __restrict__ nPart,
                           const float* __restrict__ dPart,
                           const float* __restrict__ rp,
                           float* __restrict__ loss_sum, int* __restrict__ ticket,
                           float* __restrict__ out, int M) {
    int i = blockIdx.x * blockDim.x + threadIdx.x;
    const int P = M / 128;
    float l = 0.f;
    if (i < M) {
        float rnT = 0.f, rdT = 0.f;
        for (int s = 0; s < P; ++s) {
            rnT += nPart[(size_t)s * M + i];
            rdT += dPart[(size_t)s * M + i];
        }
        int lab = labs[i];
        float fsum = 1.0f + 1e-6f;
        #pragma unroll
        for (int hb = 0; hb < HB; ++hb) fsum += hpart[hb * CCLS + lab];
        float denom = rdT / fsum + rp[i];
        l = logf(denom + 1e-12f) - logf(rnT);
    }
    l = wave_reduce_sum(l);
    __shared__ float ws_[4];
    if ((threadIdx.x & 63) == 0) ws_[threadIdx.x >> 6] = l;
    __syncthreads();
    if (threadIdx.x == 0) {
        atomicAdd(loss_sum, ws_[0] + ws_[1] + ws_[2] + ws_[3]);
        __threadfence();
        int old = atomicAdd(ticket, 1);
        if (old == (int)gridDim.x - 1) {
            __threadfence();
            out[0] = *(volatile float*)loss_sum / (float)M;
        }
    }
}

extern "C" void kernel_launch(void* const* d_in, const int* in_sizes, int n_in,
                              void* d_out, int out_size, void* d_ws, size_t ws_size,
                              hipStream_t stream) {
    const float* protos = (const float*)d_in[0];
    const float* proj2  = (const float*)d_in[1];
    const int*   t2     = (const int*)d_in[2];
    const float* proj3  = (const float*)d_in[3];
    const int*   t3     = (const int*)d_in[4];
    float* out = (float*)d_out;

    const int N = in_sizes[1] / D;   // 4096
    const int M = 2 * N;             // 8192
    const int MT = M + 128;
    const int P = M / 128;           // 64

    _Float16* ftile = (_Float16*)d_ws;                 // MT*D halfs (1KB-tiled)
    int*   labs     = (int*)(ftile + (size_t)MT * D);  // M ints
    float* hpart    = (float*)(labs + M);              // HB*CCLS
    float* nPart    = hpart + HB * CCLS;               // P*M
    float* dPart    = nPart + (size_t)P * M;           // P*M
    float* rp       = dPart + (size_t)P * M;           // M
    float* loss_sum = rp + M;                          // 1
    int*   ticket   = (int*)(loss_sum + 1);            // 1

    norm_kernel<<<(MT + 3) / 4, 256, 0, stream>>>(protos, proj2, proj3, t2, t3,
                                                  ftile, labs, hpart, loss_sum,
                                                  ticket, N, M);
    sim_kernel<<<P * (P + 1) / 2, 256, 0, stream>>>(ftile, labs, hpart,
                                                    nPart, dPart, rp, M);
    fin_kernel<<<(M + 255) / 256, 256, 0, stream>>>(labs, hpart, nPart, dPart, rp,
                                                    loss_sum, ticket, out, M);
}

// Round 17
// 68.498 us; speedup vs baseline: 1.7860x; 1.2910x over previous
//
#include <hip/hip_runtime.h>
#include <math.h>
#include <stdint.h>

#define D    128
#define CCLS 64
#define HB   8      // histogram partial blocks

typedef _Float16 f16x8 __attribute__((ext_vector_type(8)));
typedef float    f32x4 __attribute__((ext_vector_type(4)));

__device__ __forceinline__ float wave_reduce_sum(float v) {
    #pragma unroll
    for (int off = 32; off > 0; off >>= 1) v += __shfl_xor(v, off, 64);
    return v;
}

__device__ __forceinline__ void gload_lds16(const void* g, void* l) {
    __builtin_amdgcn_global_load_lds(
        (const __attribute__((address_space(1))) uint32_t*)g,
        (__attribute__((address_space(3))) uint32_t*)l, 16, 0, 0);
}

// --- normalize rows; histogram partials; labs. (same as R14) ----------------
__global__ void norm_kernel(const float* __restrict__ protos,
                            const float* __restrict__ proj2,
                            const float* __restrict__ proj3,
                            const int* __restrict__ t2, const int* __restrict__ t3,
                            _Float16* __restrict__ ftile, int* __restrict__ labs,
                            float* __restrict__ hpart, float* __restrict__ loss_sum,
                            int* __restrict__ ticket, int N, int M) {
    const float SCL = 3.8017368953f;  // sqrt(10 * log2(e))
    int w = threadIdx.x >> 6;
    int lane = threadIdx.x & 63;
    int row = blockIdx.x * (blockDim.x >> 6) + w;
    const int MT = M + 128;

    if (blockIdx.x < HB) {             // partial class histogram
        __shared__ int h[CCLS];
        int t = threadIdx.x;
        if (t < CCLS) h[t] = 0;
        __syncthreads();
        int base = blockIdx.x * (M / HB);
        for (int i = t; i < M / HB; i += (int)blockDim.x) {
            int gi = base + i;
            int lab = (gi < N) ? t2[gi] : t3[gi - N];
            atomicAdd(&h[lab], 1);
        }
        __syncthreads();
        if (t < CCLS) hpart[blockIdx.x * CCLS + t] = (float)h[t];
    }
    if (blockIdx.x == HB && threadIdx.x == 0) { loss_sum[0] = 0.f; ticket[0] = 0; }

    if (row < MT) {
        const float* src = nullptr;
        if (row < M)             src = (row < N) ? proj2 + (size_t)row * D
                                                 : proj3 + (size_t)(row - N) * D;
        else if (row < M + CCLS) src = protos + (size_t)(row - M) * D;
        float2 v = {0.f, 0.f};
        if (src) v = ((const float2*)src)[lane];
        float ss = wave_reduce_sum(v.x * v.x + v.y * v.y);
        float scale = src ? SCL / fmaxf(sqrtf(ss), 1e-12f) : 0.f;
        _Float16 h0 = (_Float16)(v.x * scale), h1 = (_Float16)(v.y * scale);
        int k0 = 2 * lane;
        size_t off = ((size_t)(row >> 4) * 16 + (k0 >> 3)) * 128 + (row & 15) * 8 + (k0 & 7);
        ftile[off] = h0; ftile[off + 1] = h1;
        if (row < M && lane == 0)
            labs[row] = (row < N) ? t2[row] : t3[row - N];
    }
}

// --- main: SYMMETRIC pair blocks (pi <= pj): tile computed once, row sums ->
//     slot pj, col sums -> slot pi. R16 regression root-caused: full unroll
//     of the 8-iter n-loop let the scheduler pipeline all 8 bodies -> VGPR
//     blowup -> 122MB scratch spill. Fix: #pragma unroll 2 caps live range;
//     all per-body register array indices remain static (rule #20).
__global__ __launch_bounds__(256, 4)
void sim_kernel(const _Float16* __restrict__ ftile,
                const int* __restrict__ labs,
                const float* __restrict__ hpart,
                float* __restrict__ nPart, float* __restrict__ dPart,
                float* __restrict__ rp, int M) {
    __shared__ __align__(16) _Float16 Bl[16384];   // 32KB: pj panel fragments
    __shared__ int labL[128];
    __shared__ float colp[4][2][4][32];            // [wave][d/n][r][n*4+g]

    const int P = M / 128;                          // 64 panels
    int b = blockIdx.x, pi = 0, rem = P;
    while (b >= rem) { b -= rem; --rem; ++pi; }
    const int pj = pi + b;
    const bool diagB = (pi == pj);

    const int t = threadIdx.x;
    const int w = t >> 6, lane = t & 63;
    const int g = lane >> 4, li = lane & 15;
    const int lo = g * 128 + li * 8;

    // stage B-panel (32KB contiguous in tiled layout) + pj labels
    {
        const char* src = (const char*)(ftile + (size_t)pj * 16384);
        char* dst = (char*)Bl;
        #pragma unroll
        for (int q = 0; q < 8; ++q)
            gload_lds16(src + (size_t)(w * 8 + q) * 1024 + lane * 16,
                        dst + (size_t)(w * 8 + q) * 1024);
    }
    if (t >= 128) labL[t - 128] = labs[pj * 128 + (t - 128)];

    // A fragments: this wave's 32 rows x 128 k (direct from L2)
    const int rtA = pi * 8 + w * 2;
    f16x8 a[2][4];
    #pragma unroll
    for (int m = 0; m < 2; ++m)
        #pragma unroll
        for (int kt = 0; kt < 4; ++kt)
            a[m][kt] = *(const f16x8*)(ftile + (size_t)(rtA + m) * 2048 + kt * 512 + lo);

    const int row0 = pi * 128 + 32 * w + li;
    const int rl0 = labs[row0];
    const int rl1 = labs[row0 + 16];
    float rn[2] = {0.f, 0.f}, rd[2] = {0.f, 0.f};

    __syncthreads();   // drains global_load_lds (vmcnt) + labL writes

    #pragma unroll 2
    for (int n = 0; n < 8; ++n) {
        f16x8 bn[4];
        #pragma unroll
        for (int kt = 0; kt < 4; ++kt)
            bn[kt] = *(const f16x8*)(Bl + n * 2048 + kt * 512 + lo);

        f32x4 acc[2];
        #pragma unroll
        for (int m = 0; m < 2; ++m)
            #pragma unroll
            for (int r = 0; r < 4; ++r) acc[m][r] = 0.f;

        #pragma unroll
        for (int kt = 0; kt < 4; ++kt)
            #pragma unroll
            for (int m = 0; m < 2; ++m)
                acc[m] = __builtin_amdgcn_mfma_f32_16x16x32_f16(bn[kt], a[m][kt], acc[m], 0, 0, 0);

        if (diagB) {   // i==j mask: row's 16-block is 2w+m; col block is n
            #pragma unroll
            for (int m = 0; m < 2; ++m)
                #pragma unroll
                for (int r = 0; r < 4; ++r)
                    acc[m][r] = (n == 2 * w + m && 4 * g + r == li) ? -1e5f : acc[m][r];
        }

        int4 c4 = *(const int4*)(labL + n * 16 + 4 * g);
        float rcd[4] = {0.f, 0.f, 0.f, 0.f};
        float rcn[4] = {0.f, 0.f, 0.f, 0.f};
        #pragma unroll
        for (int m = 0; m < 2; ++m) {
            float e0 = __builtin_amdgcn_exp2f(acc[m][0]);
            float e1 = __builtin_amdgcn_exp2f(acc[m][1]);
            float e2 = __builtin_amdgcn_exp2f(acc[m][2]);
            float e3 = __builtin_amdgcn_exp2f(acc[m][3]);
            const int rl = m ? rl1 : rl0;
            float s0 = (c4.x == rl) ? e0 : 0.f;
            float s1 = (c4.y == rl) ? e1 : 0.f;
            float s2 = (c4.z == rl) ? e2 : 0.f;
            float s3 = (c4.w == rl) ? e3 : 0.f;
            rd[m] += (e0 + e1) + (e2 + e3);
            rn[m] += (s0 + s1) + (s2 + s3);
            rcd[0] += e0; rcd[1] += e1; rcd[2] += e2; rcd[3] += e3;
            rcn[0] += s0; rcn[1] += s1; rcn[2] += s2; rcn[3] += s3;
        }

        if (!diagB) {
            #pragma unroll
            for (int r = 0; r < 4; ++r) {
                #pragma unroll
                for (int off = 1; off < 16; off <<= 1) {
                    rcd[r] += __shfl_xor(rcd[r], off, 64);
                    rcn[r] += __shfl_xor(rcn[r], off, 64);
                }
            }
            if (li == 0) {
                #pragma unroll
                for (int r = 0; r < 4; ++r) {
                    colp[w][0][r][n * 4 + g] = rcd[r];
                    colp[w][1][r][n * 4 + g] = rcn[r];
                }
            }
        }
    }

    // proto slice (diag blocks only): rp = sum_c e/freq_c; numer += e[lab]
    float rpacc[2] = {0.f, 0.f};
    if (diagB) {
        const int rbp = M >> 4;
        #pragma unroll 2
        for (int n = 0; n < 4; ++n) {
            f16x8 bn[4];
            #pragma unroll
            for (int kt = 0; kt < 4; ++kt)
                bn[kt] = *(const f16x8*)(ftile + (size_t)(rbp + n) * 2048 + kt * 512 + lo);
            f32x4 acc[2];
            #pragma unroll
            for (int m = 0; m < 2; ++m)
                #pragma unroll
                for (int r = 0; r < 4; ++r) acc[m][r] = 0.f;
            #pragma unroll
            for (int kt = 0; kt < 4; ++kt)
                #pragma unroll
                for (int m = 0; m < 2; ++m)
                    acc[m] = __builtin_amdgcn_mfma_f32_16x16x32_f16(bn[kt], a[m][kt], acc[m], 0, 0, 0);

            f32x4 fr = {1.0f + 1e-6f, 1.0f + 1e-6f, 1.0f + 1e-6f, 1.0f + 1e-6f};
            #pragma unroll
            for (int hb = 0; hb < HB; ++hb)
                fr += *(const f32x4*)(hpart + hb * CCLS + 16 * n + 4 * g);
            const int c0 = 16 * n + 4 * g;
            #pragma unroll
            for (int m = 0; m < 2; ++m) {
                float e0 = __builtin_amdgcn_exp2f(acc[m][0]);
                float e1 = __builtin_amdgcn_exp2f(acc[m][1]);
                float e2 = __builtin_amdgcn_exp2f(acc[m][2]);
                float e3 = __builtin_amdgcn_exp2f(acc[m][3]);
                const int rl = m ? rl1 : rl0;
                rpacc[m] += e0 / fr[0] + e1 / fr[1] + e2 / fr[2] + e3 / fr[3];
                rn[m] += (c0 + 0 == rl) ? e0 : 0.f;
                rn[m] += (c0 + 1 == rl) ? e1 : 0.f;
                rn[m] += (c0 + 2 == rl) ? e2 : 0.f;
                rn[m] += (c0 + 3 == rl) ? e3 : 0.f;
            }
        }
    }

    // row side: reduce over g, store slot pj
    #pragma unroll
    for (int m = 0; m < 2; ++m) {
        rn[m] += __shfl_xor(rn[m], 16, 64); rn[m] += __shfl_xor(rn[m], 32, 64);
        rd[m] += __shfl_xor(rd[m], 16, 64); rd[m] += __shfl_xor(rd[m], 32, 64);
        if (diagB) {
            rpacc[m] += __shfl_xor(rpacc[m], 16, 64);
            rpacc[m] += __shfl_xor(rpacc[m], 32, 64);
        }
    }
    if (lane < 16) {
        #pragma unroll
        for (int m = 0; m < 2; ++m) {
            const int rowm = row0 + 16 * m;
            nPart[(size_t)pj * M + rowm] = rn[m];
            dPart[(size_t)pj * M + rowm] = rd[m];
            if (diagB) rp[rowm] = rpacc[m];
        }
    }

    // col side: cross-wave fold, store slot pi (rows of panel pj)
    __syncthreads();
    if (!diagB && t < 128) {
        const int j = t, nn = j >> 4, gg = (j >> 2) & 3, rr = j & 3;
        float sd = colp[0][0][rr][nn * 4 + gg] + colp[1][0][rr][nn * 4 + gg]
                 + colp[2][0][rr][nn * 4 + gg] + colp[3][0][rr][nn * 4 + gg];
        float sn = colp[0][1][rr][nn * 4 + gg] + colp[1][1][rr][nn * 4 + gg]
                 + colp[2][1][rr][nn * 4 + gg] + colp[3][1][rr][nn * 4 + gg];
        dPart[(size_t)pi * M + pj * 128 + j] = sd;
        nPart[(size_t)pi * M + pj * 128 + j] = sn;
    }
}

// --- per-row loss + mean accumulate; last block writes output ----------------
__global__ void fin_kernel(const int* __restrict__ labs,
                           const float* __restrict__ hpart,
                           const float* __restrict__ nPart,
                           const float* __restrict__ dPart,
                           const float* __restrict__ rp,
                           float* __restrict__ loss_sum, int* __restrict__ ticket,
                           float* __restrict__ out, int M) {
    int i = blockIdx.x * blockDim.x + threadIdx.x;
    const int P = M / 128;
    float l = 0.f;
    if (i < M) {
        float rnT = 0.f, rdT = 0.f;
        for (int s = 0; s < P; ++s) {
            rnT += nPart[(size_t)s * M + i];
            rdT += dPart[(size_t)s * M + i];
        }
        int lab = labs[i];
        float fsum = 1.0f + 1e-6f;
        #pragma unroll
        for (int hb = 0; hb < HB; ++hb) fsum += hpart[hb * CCLS + lab];
        float denom = rdT / fsum + rp[i];
        l = logf(denom + 1e-12f) - logf(rnT);
    }
    l = wave_reduce_sum(l);
    __shared__ float ws_[4];
    if ((threadIdx.x & 63) == 0) ws_[threadIdx.x >> 6] = l;
    __syncthreads();
    if (threadIdx.x == 0) {
        atomicAdd(loss_sum, ws_[0] + ws_[1] + ws_[2] + ws_[3]);
        __threadfence();
        int old = atomicAdd(ticket, 1);
        if (old == (int)gridDim.x - 1) {
            __threadfence();
            out[0] = *(volatile float*)loss_sum / (float)M;
        }
    }
}

extern "C" void kernel_launch(void* const* d_in, const int* in_sizes, int n_in,
                              void* d_out, int out_size, void* d_ws, size_t ws_size,
                              hipStream_t stream) {
    const float* protos = (const float*)d_in[0];
    const float* proj2  = (const float*)d_in[1];
    const int*   t2     = (const int*)d_in[2];
    const float* proj3  = (const float*)d_in[3];
    const int*   t3     = (const int*)d_in[4];
    float* out = (float*)d_out;

    const int N = in_sizes[1] / D;   // 4096
    const int M = 2 * N;             // 8192
    const int MT = M + 128;
    const int P = M / 128;           // 64

    _Float16* ftile = (_Float16*)d_ws;                 // MT*D halfs (1KB-tiled)
    int*   labs     = (int*)(ftile + (size_t)MT * D);  // M ints
    float* hpart    = (float*)(labs + M);              // HB*CCLS
    float* nPart    = hpart + HB * CCLS;               // P*M
    float* dPart    = nPart + (size_t)P * M;           // P*M
    float* rp       = dPart + (size_t)P * M;           // M
    float* loss_sum = rp + M;                          // 1
    int*   ticket   = (int*)(loss_sum + 1);            // 1

    norm_kernel<<<(MT + 3) / 4, 256, 0, stream>>>(protos, proj2, proj3, t2, t3,
                                                  ftile, labs, hpart, loss_sum,
                                                  ticket, N, M);
    sim_kernel<<<P * (P + 1) / 2, 256, 0, stream>>>(ftile, labs, hpart,
                                                    nPart, dPart, rp, M);
    fin_kernel<<<(M + 255) / 256, 256, 0, stream>>>(labs, hpart, nPart, dPart, rp,
                                                    loss_sum, ticket, out, M);
}

// Round 18
// 56.605 us; speedup vs baseline: 2.1612x; 1.2101x over previous
//
#include <hip/hip_runtime.h>
#include <math.h>
#include <stdint.h>

#define D    128
#define CCLS 64
#define HB   8      // histogram partial blocks

typedef _Float16 f16x8 __attribute__((ext_vector_type(8)));
typedef _Float16 f16x2 __attribute__((ext_vector_type(2)));
typedef float    f32x4 __attribute__((ext_vector_type(4)));

__device__ __forceinline__ float wave_reduce_sum(float v) {
    #pragma unroll
    for (int off = 32; off > 0; off >>= 1) v += __shfl_xor(v, off, 64);
    return v;
}

__device__ __forceinline__ void gload_lds16(const void* g, void* l) {
    __builtin_amdgcn_global_load_lds(
        (const __attribute__((address_space(1))) uint32_t*)g,
        (__attribute__((address_space(3))) uint32_t*)l, 16, 0, 0);
}

// --- normalize rows; histogram partials; labs. (same as R14) ----------------
__global__ void norm_kernel(const float* __restrict__ protos,
                            const float* __restrict__ proj2,
                            const float* __restrict__ proj3,
                            const int* __restrict__ t2, const int* __restrict__ t3,
                            _Float16* __restrict__ ftile, int* __restrict__ labs,
                            float* __restrict__ hpart, float* __restrict__ loss_sum,
                            int* __restrict__ ticket, int N, int M) {
    const float SCL = 3.8017368953f;  // sqrt(10 * log2(e))
    int w = threadIdx.x >> 6;
    int lane = threadIdx.x & 63;
    int row = blockIdx.x * (blockDim.x >> 6) + w;
    const int MT = M + 128;

    if (blockIdx.x < HB) {             // partial class histogram
        __shared__ int h[CCLS];
        int t = threadIdx.x;
        if (t < CCLS) h[t] = 0;
        __syncthreads();
        int base = blockIdx.x * (M / HB);
        for (int i = t; i < M / HB; i += (int)blockDim.x) {
            int gi = base + i;
            int lab = (gi < N) ? t2[gi] : t3[gi - N];
            atomicAdd(&h[lab], 1);
        }
        __syncthreads();
        if (t < CCLS) hpart[blockIdx.x * CCLS + t] = (float)h[t];
    }
    if (blockIdx.x == HB && threadIdx.x == 0) { loss_sum[0] = 0.f; ticket[0] = 0; }

    if (row < MT) {
        const float* src = nullptr;
        if (row < M)             src = (row < N) ? proj2 + (size_t)row * D
                                                 : proj3 + (size_t)(row - N) * D;
        else if (row < M + CCLS) src = protos + (size_t)(row - M) * D;
        float2 v = {0.f, 0.f};
        if (src) v = ((const float2*)src)[lane];
        float ss = wave_reduce_sum(v.x * v.x + v.y * v.y);
        float scale = src ? SCL / fmaxf(sqrtf(ss), 1e-12f) : 0.f;
        _Float16 h0 = (_Float16)(v.x * scale), h1 = (_Float16)(v.y * scale);
        int k0 = 2 * lane;
        size_t off = ((size_t)(row >> 4) * 16 + (k0 >> 3)) * 128 + (row & 15) * 8 + (k0 & 7);
        ftile[off] = h0; ftile[off + 1] = h1;
        if (row < M && lane == 0)
            labs[row] = (row < N) ? t2[row] : t3[row - N];
    }
}

// --- main: SYMMETRIC pair blocks (pi <= pj). R17 regression root-caused:
//     col fold used 256 shfl_xor/thread = ds_bpermute storm -> DS pipe
//     saturated (~20us/CU), MfmaUtil 7%. R18 fold: pack (rcd,rcn) as f16x2,
//     ONE shfl_xor(8)+pk_add per r (16->8 lanes), lanes li<8 write one b128
//     to colS[4][8][136]; 128-thread unpack-fold at the end. ~8x fewer DS
//     wave-ops. Row side unchanged (slot pj); col side -> slot pi.
__global__ __launch_bounds__(256, 3)
void sim_kernel(const _Float16* __restrict__ ftile,
                const int* __restrict__ labs,
                const float* __restrict__ hpart,
                float* __restrict__ nPart, float* __restrict__ dPart,
                float* __restrict__ rp, int M) {
    __shared__ __align__(16) _Float16 Bl[16384];   // 32KB: pj panel fragments
    __shared__ int labL[128];
    __shared__ __align__(16) uint32_t colS[4][8][136];  // packed (rcd,rcn) partials

    const int P = M / 128;                          // 64 panels
    int b = blockIdx.x, pi = 0, rem = P;
    while (b >= rem) { b -= rem; --rem; ++pi; }
    const int pj = pi + b;
    const bool diagB = (pi == pj);

    const int t = threadIdx.x;
    const int w = t >> 6, lane = t & 63;
    const int g = lane >> 4, li = lane & 15;
    const int lo = g * 128 + li * 8;

    // stage B-panel (32KB contiguous in tiled layout) + pj labels
    {
        const char* src = (const char*)(ftile + (size_t)pj * 16384);
        char* dst = (char*)Bl;
        #pragma unroll
        for (int q = 0; q < 8; ++q)
            gload_lds16(src + (size_t)(w * 8 + q) * 1024 + lane * 16,
                        dst + (size_t)(w * 8 + q) * 1024);
    }
    if (t >= 128) labL[t - 128] = labs[pj * 128 + (t - 128)];

    // A fragments: this wave's 32 rows x 128 k (direct from L2)
    const int rtA = pi * 8 + w * 2;
    f16x8 a[2][4];
    #pragma unroll
    for (int m = 0; m < 2; ++m)
        #pragma unroll
        for (int kt = 0; kt < 4; ++kt)
            a[m][kt] = *(const f16x8*)(ftile + (size_t)(rtA + m) * 2048 + kt * 512 + lo);

    const int row0 = pi * 128 + 32 * w + li;
    const int rl0 = labs[row0];
    const int rl1 = labs[row0 + 16];
    float rn[2] = {0.f, 0.f}, rd[2] = {0.f, 0.f};

    __syncthreads();   // drains global_load_lds (vmcnt) + labL writes

    #pragma unroll 2
    for (int n = 0; n < 8; ++n) {
        f16x8 bn[4];
        #pragma unroll
        for (int kt = 0; kt < 4; ++kt)
            bn[kt] = *(const f16x8*)(Bl + n * 2048 + kt * 512 + lo);

        f32x4 acc[2];
        #pragma unroll
        for (int m = 0; m < 2; ++m)
            #pragma unroll
            for (int r = 0; r < 4; ++r) acc[m][r] = 0.f;

        #pragma unroll
        for (int kt = 0; kt < 4; ++kt)
            #pragma unroll
            for (int m = 0; m < 2; ++m)
                acc[m] = __builtin_amdgcn_mfma_f32_16x16x32_f16(bn[kt], a[m][kt], acc[m], 0, 0, 0);

        if (diagB) {   // i==j mask: row's 16-block is 2w+m; col block is n
            #pragma unroll
            for (int m = 0; m < 2; ++m)
                #pragma unroll
                for (int r = 0; r < 4; ++r)
                    acc[m][r] = (n == 2 * w + m && 4 * g + r == li) ? -1e5f : acc[m][r];
        }

        int4 c4 = *(const int4*)(labL + n * 16 + 4 * g);
        float rcd[4] = {0.f, 0.f, 0.f, 0.f};
        float rcn[4] = {0.f, 0.f, 0.f, 0.f};
        #pragma unroll
        for (int m = 0; m < 2; ++m) {
            float e0 = __builtin_amdgcn_exp2f(acc[m][0]);
            float e1 = __builtin_amdgcn_exp2f(acc[m][1]);
            float e2 = __builtin_amdgcn_exp2f(acc[m][2]);
            float e3 = __builtin_amdgcn_exp2f(acc[m][3]);
            const int rl = m ? rl1 : rl0;
            float s0 = (c4.x == rl) ? e0 : 0.f;
            float s1 = (c4.y == rl) ? e1 : 0.f;
            float s2 = (c4.z == rl) ? e2 : 0.f;
            float s3 = (c4.w == rl) ? e3 : 0.f;
            rd[m] += (e0 + e1) + (e2 + e3);
            rn[m] += (s0 + s1) + (s2 + s3);
            rcd[0] += e0; rcd[1] += e1; rcd[2] += e2; rcd[3] += e3;
            rcn[0] += s0; rcn[1] += s1; rcn[2] += s2; rcn[3] += s3;
        }

        if (!diagB) {
            // pack (rcd,rcn) -> f16x2 (max 2*e^10 = 44052 < f16 max), one
            // shfl_xor(8) + pk_add folds li 16->8, li<8 writes one b128.
            f16x2 pk0 = {(_Float16)rcd[0], (_Float16)rcn[0]};
            f16x2 pk1 = {(_Float16)rcd[1], (_Float16)rcn[1]};
            f16x2 pk2 = {(_Float16)rcd[2], (_Float16)rcn[2]};
            f16x2 pk3 = {(_Float16)rcd[3], (_Float16)rcn[3]};
            int o0 = __shfl_xor(__builtin_bit_cast(int, pk0), 8, 64);
            int o1 = __shfl_xor(__builtin_bit_cast(int, pk1), 8, 64);
            int o2 = __shfl_xor(__builtin_bit_cast(int, pk2), 8, 64);
            int o3 = __shfl_xor(__builtin_bit_cast(int, pk3), 8, 64);
            pk0 += __builtin_bit_cast(f16x2, o0);
            pk1 += __builtin_bit_cast(f16x2, o1);
            pk2 += __builtin_bit_cast(f16x2, o2);
            pk3 += __builtin_bit_cast(f16x2, o3);
            if (li < 8) {
                uint4 val = { __builtin_bit_cast(uint32_t, pk0),
                              __builtin_bit_cast(uint32_t, pk1),
                              __builtin_bit_cast(uint32_t, pk2),
                              __builtin_bit_cast(uint32_t, pk3) };
                *(uint4*)&colS[w][li][n * 16 + 4 * g] = val;
            }
        }
    }

    // proto slice (diag blocks only): rp = sum_c e/freq_c; numer += e[lab]
    float rpacc[2] = {0.f, 0.f};
    if (diagB) {
        const int rbp = M >> 4;
        #pragma unroll 2
        for (int n = 0; n < 4; ++n) {
            f16x8 bn[4];
            #pragma unroll
            for (int kt = 0; kt < 4; ++kt)
                bn[kt] = *(const f16x8*)(ftile + (size_t)(rbp + n) * 2048 + kt * 512 + lo);
            f32x4 acc[2];
            #pragma unroll
            for (int m = 0; m < 2; ++m)
                #pragma unroll
                for (int r = 0; r < 4; ++r) acc[m][r] = 0.f;
            #pragma unroll
            for (int kt = 0; kt < 4; ++kt)
                #pragma unroll
                for (int m = 0; m < 2; ++m)
                    acc[m] = __builtin_amdgcn_mfma_f32_16x16x32_f16(bn[kt], a[m][kt], acc[m], 0, 0, 0);

            f32x4 fr = {1.0f + 1e-6f, 1.0f + 1e-6f, 1.0f + 1e-6f, 1.0f + 1e-6f};
            #pragma unroll
            for (int hb = 0; hb < HB; ++hb)
                fr += *(const f32x4*)(hpart + hb * CCLS + 16 * n + 4 * g);
            const int c0 = 16 * n + 4 * g;
            #pragma unroll
            for (int m = 0; m < 2; ++m) {
                float e0 = __builtin_amdgcn_exp2f(acc[m][0]);
                float e1 = __builtin_amdgcn_exp2f(acc[m][1]);
                float e2 = __builtin_amdgcn_exp2f(acc[m][2]);
                float e3 = __builtin_amdgcn_exp2f(acc[m][3]);
                const int rl = m ? rl1 : rl0;
                rpacc[m] += e0 / fr[0] + e1 / fr[1] + e2 / fr[2] + e3 / fr[3];
                rn[m] += (c0 + 0 == rl) ? e0 : 0.f;
                rn[m] += (c0 + 1 == rl) ? e1 : 0.f;
                rn[m] += (c0 + 2 == rl) ? e2 : 0.f;
                rn[m] += (c0 + 3 == rl) ? e3 : 0.f;
            }
        }
    }

    // row side: reduce over g, store slot pj
    #pragma unroll
    for (int m = 0; m < 2; ++m) {
        rn[m] += __shfl_xor(rn[m], 16, 64); rn[m] += __shfl_xor(rn[m], 32, 64);
        rd[m] += __shfl_xor(rd[m], 16, 64); rd[m] += __shfl_xor(rd[m], 32, 64);
        if (diagB) {
            rpacc[m] += __shfl_xor(rpacc[m], 16, 64);
            rpacc[m] += __shfl_xor(rpacc[m], 32, 64);
        }
    }
    if (lane < 16) {
        #pragma unroll
        for (int m = 0; m < 2; ++m) {
            const int rowm = row0 + 16 * m;
            nPart[(size_t)pj * M + rowm] = rn[m];
            dPart[(size_t)pj * M + rowm] = rd[m];
            if (diagB) rp[rowm] = rpacc[m];
        }
    }

    // col side: unpack-fold colS, store slot pi (rows of panel pj)
    __syncthreads();
    if (!diagB && t < 128) {
        const int j = t;
        float sd = 0.f, sn = 0.f;
        #pragma unroll
        for (int w4 = 0; w4 < 4; ++w4)
            #pragma unroll
            for (int l8 = 0; l8 < 8; ++l8) {
                f16x2 h = __builtin_bit_cast(f16x2, colS[w4][l8][j]);
                sd += (float)h.x;
                sn += (float)h.y;
            }
        dPart[(size_t)pi * M + pj * 128 + j] = sd;
        nPart[(size_t)pi * M + pj * 128 + j] = sn;
    }
}

// --- per-row loss + mean accumulate; last block writes output ----------------
__global__ void fin_kernel(const int* __restrict__ labs,
                           const float* __restrict__ hpart,
                           const float* __restrict__ nPart,
                           const float* __restrict__ dPart,
                           const float* __restrict__ rp,
                           float* __restrict__ loss_sum, int* __restrict__ ticket,
                           float* __restrict__ out, int M) {
    int i = blockIdx.x * blockDim.x + threadIdx.x;
    const int P = M / 128;
    float l = 0.f;
    if (i < M) {
        float rnT = 0.f, rdT = 0.f;
        for (int s = 0; s < P; ++s) {
            rnT += nPart[(size_t)s * M + i];
            rdT += dPart[(size_t)s * M + i];
        }
        int lab = labs[i];
        float fsum = 1.0f + 1e-6f;
        #pragma unroll
        for (int hb = 0; hb < HB; ++hb) fsum += hpart[hb * CCLS + lab];
        float denom = rdT / fsum + rp[i];
        l = logf(denom + 1e-12f) - logf(rnT);
    }
    l = wave_reduce_sum(l);
    __shared__ float ws_[4];
    if ((threadIdx.x & 63) == 0) ws_[threadIdx.x >> 6] = l;
    __syncthreads();
    if (threadIdx.x == 0) {
        atomicAdd(loss_sum, ws_[0] + ws_[1] + ws_[2] + ws_[3]);
        __threadfence();
        int old = atomicAdd(ticket, 1);
        if (old == (int)gridDim.x - 1) {
            __threadfence();
            out[0] = *(volatile float*)loss_sum / (float)M;
        }
    }
}

extern "C" void kernel_launch(void* const* d_in, const int* in_sizes, int n_in,
                              void* d_out, int out_size, void* d_ws, size_t ws_size,
                              hipStream_t stream) {
    const float* protos = (const float*)d_in[0];
    const float* proj2  = (const float*)d_in[1];
    const int*   t2     = (const int*)d_in[2];
    const float* proj3  = (const float*)d_in[3];
    const int*   t3     = (const int*)d_in[4];
    float* out = (float*)d_out;

    const int N = in_sizes[1] / D;   // 4096
    const int M = 2 * N;             // 8192
    const int MT = M + 128;
    const int P = M / 128;           // 64

    _Float16* ftile = (_Float16*)d_ws;                 // MT*D halfs (1KB-tiled)
    int*   labs     = (int*)(ftile + (size_t)MT * D);  // M ints
    float* hpart    = (float*)(labs + M);              // HB*CCLS
    float* nPart    = hpart + HB * CCLS;               // P*M
    float* dPart    = nPart + (size_t)P * M;           // P*M
    float* rp       = dPart + (size_t)P * M;           // M
    float* loss_sum = rp + M;                          // 1
    int*   ticket   = (int*)(loss_sum + 1);            // 1

    norm_kernel<<<(MT + 3) / 4, 256, 0, stream>>>(protos, proj2, proj3, t2, t3,
                                                  ftile, labs, hpart, loss_sum,
                                                  ticket, N, M);
    sim_kernel<<<P * (P + 1) / 2, 256, 0, stream>>>(ftile, labs, hpart,
                                                    nPart, dPart, rp, M);
    fin_kernel<<<(M + 255) / 256, 256, 0, stream>>>(labs, hpart, nPart, dPart, rp,
                                                    loss_sum, ticket, out, M);
}